// Round 4
// baseline (80.641 us; speedup 1.0000x reference)
//
#include <hip/hip_runtime.h>

#define BB 384
#define DD 256           // floats per row; 64 float4
#define F4 (DD / 4)      // 64
#define APB 2            // anchors per block
#define NBLK (BB / APB)  // 192 blocks
#define MARGIN 0.2f
#define POISON64 0xAAAAAAAAAAAAAAAAULL

union du64 { double d; unsigned long long u; };

// ---------------------------------------------------------------------------
// Single fused kernel: 192 blocks, 2 anchors each.
//   Phase 1: dist rows (segment-coalesced loads, register anchor fragments,
//            16-lane shfl_xor butterfly) — unchanged from the passing R3 kernel.
//   Phase 2: per-anchor positive list via LDS atomics + triplet relu sum,
//            accumulated per-block into (blk_num, blk_den) on thread 0.
//   Phase 3: thread 0 stores num (relaxed) then den+1 (release) to agent-scope
//            workspace slots. den+1 >= 1.0 so its bit pattern can never equal
//            the 0xAA poison NOR zero — block 0 polls for "neither poison nor
//            zero", making the handshake robust to either workspace init.
//   Phase 4: block 0 polls all 192 slots (one per thread, acquire), reduces,
//            writes the scalar loss. All 192 blocks are co-resident on 256
//            CUs, so the poll cannot deadlock.
// ---------------------------------------------------------------------------
__global__ __launch_bounds__(256) void triplet_onekernel(
    const float* __restrict__ x,
    const int* __restrict__ labels,
    unsigned long long* __restrict__ slot_num,
    unsigned long long* __restrict__ slot_den,
    float* __restrict__ out) {
    __shared__ int    s_lab[BB];
    __shared__ float  s_d[APB][BB];
    __shared__ int    s_pos[BB];
    __shared__ int    s_np, s_cnt;
    __shared__ double s_red[4];
    __shared__ double s_redd[4];

    const int tid  = threadIdx.x;
    const int wave = tid >> 6;
    const int lane = tid & 63;
    const int rr   = lane >> 4;   // row-within-quad: 0..3
    const int dd   = lane & 15;   // dim-segment lane: 0..15
    const int a0   = blockIdx.x * APB;

    const float4* x4 = reinterpret_cast<const float4*>(x);

    for (int i = tid; i < BB; i += 256) s_lab[i] = labels[i];

    // Anchor fragments in registers: xa[j][k] = float4 f = 16k + dd of row a0+j.
    float4 xa[APB][4];
#pragma unroll
    for (int j = 0; j < APB; ++j)
#pragma unroll
        for (int k = 0; k < 4; ++k)
            xa[j][k] = x4[(a0 + j) * F4 + k * 16 + dd];

    // ---- Phase 1: dist rows, each wave covers 96 rows, 4 per iteration ----
    for (int b0 = wave * 96; b0 < wave * 96 + 96; b0 += 4) {
        const int b = b0 + rr;
        float4 row[4];
#pragma unroll
        for (int k = 0; k < 4; ++k)
            row[k] = x4[b * F4 + k * 16 + dd];

        float s[APB];
#pragma unroll
        for (int j = 0; j < APB; ++j) {
            float sx = 0.f, sy = 0.f, sz = 0.f, sw = 0.f;
#pragma unroll
            for (int k = 0; k < 4; ++k) {
                float dx = row[k].x - xa[j][k].x;
                float dy = row[k].y - xa[j][k].y;
                float dz = row[k].z - xa[j][k].z;
                float dw = row[k].w - xa[j][k].w;
                sx += dx * dx;
                sy += dy * dy;
                sz += dz * dz;
                sw += dw * dw;
            }
            s[j] = (sx + sy) + (sz + sw);
        }
#pragma unroll
        for (int mask = 1; mask < 16; mask <<= 1)
#pragma unroll
            for (int j = 0; j < APB; ++j)
                s[j] += __shfl_xor(s[j], mask, 64);

        if (dd == 0) s_d[0][b] = s[0];
        if (dd == 1) s_d[1][b] = s[1];
    }
    __syncthreads();

    // ---- Phase 2: triplet sums for anchors a0, a0+1 ----
    double blk_num = 0.0, blk_den = 0.0;
    for (int j = 0; j < APB; ++j) {
        const int a = a0 + j;
        if (tid == 0) { s_np = 0; s_cnt = 0; }
        __syncthreads();

        const int la = s_lab[a];
        for (int i = tid; i < BB; i += 256) {
            if (s_lab[i] == la) {
                atomicAdd(&s_cnt, 1);
                if (i > a) {
                    int k = atomicAdd(&s_np, 1);
                    s_pos[k] = i;
                }
            }
        }
        __syncthreads();

        const int np = s_np;
        const int cnt = s_cnt;

        double num_local = 0.0;
        for (int pi = 0; pi < np; ++pi) {
            const float t = MARGIN + s_d[j][s_pos[pi]];
            for (int n = tid; n < BB; n += 256) {
                if (s_lab[n] != la) {
                    float l = t - s_d[j][n];
                    if (l > 0.f) num_local += (double)l;
                }
            }
        }

        for (int off = 32; off > 0; off >>= 1)
            num_local += __shfl_down(num_local, off, 64);
        if (lane == 0) s_red[wave] = num_local;
        __syncthreads();

        if (tid == 0) {
            double tot = (s_red[0] + s_red[1]) + (s_red[2] + s_red[3]);
            blk_num += tot * (double)cnt;
            blk_den += (double)cnt * (double)np * (double)(BB - cnt);
        }
        __syncthreads();  // protect s_np/s_cnt/s_red reuse
    }

    // ---- Phase 3: publish per-block partials (agent scope, release) ----
    if (tid == 0) {
        du64 n; n.d = blk_num;
        __hip_atomic_store(&slot_num[blockIdx.x], n.u,
                           __ATOMIC_RELAXED, __HIP_MEMORY_SCOPE_AGENT);
        du64 d; d.d = blk_den + 1.0;   // >= 1.0: never poison, never zero
        __hip_atomic_store(&slot_den[blockIdx.x], d.u,
                           __ATOMIC_RELEASE, __HIP_MEMORY_SCOPE_AGENT);
    }

    // ---- Phase 4: block 0 gathers + finalizes ----
    if (blockIdx.x == 0) {
        double n_l = 0.0, d_l = 0.0;
        if (tid < NBLK) {
            unsigned long long ud;
            do {
                ud = __hip_atomic_load(&slot_den[tid],
                                       __ATOMIC_ACQUIRE, __HIP_MEMORY_SCOPE_AGENT);
            } while (ud == POISON64 || ud == 0ULL);
            du64 d; d.u = ud;
            d_l = d.d - 1.0;
            du64 n;
            n.u = __hip_atomic_load(&slot_num[tid],
                                    __ATOMIC_RELAXED, __HIP_MEMORY_SCOPE_AGENT);
            n_l = n.d;
        }
        for (int off = 32; off > 0; off >>= 1) {
            n_l += __shfl_down(n_l, off, 64);
            d_l += __shfl_down(d_l, off, 64);
        }
        if (lane == 0) { s_red[wave] = n_l; s_redd[wave] = d_l; }
        __syncthreads();

        if (tid == 0) {
            double num = (s_red[0] + s_red[1]) + (s_red[2] + s_red[3]);
            double den = (s_redd[0] + s_redd[1]) + (s_redd[2] + s_redd[3]);
            out[0] = (den > 0.0) ? (float)(num / den) : 0.0f;
        }
    }
}

extern "C" void kernel_launch(void* const* d_in, const int* in_sizes, int n_in,
                              void* d_out, int out_size, void* d_ws, size_t ws_size,
                              hipStream_t stream) {
    const float* x = (const float*)d_in[0];
    const int* labels = (const int*)d_in[1];
    float* out = (float*)d_out;

    unsigned long long* slot_num = (unsigned long long*)d_ws;
    unsigned long long* slot_den = slot_num + NBLK;

    triplet_onekernel<<<NBLK, 256, 0, stream>>>(x, labels, slot_num, slot_den, out);
}